// Round 1
// baseline (717.491 us; speedup 1.0000x reference)
//
#include <hip/hip_runtime.h>
#include <math.h>

// Problem constants
#define TT 16384   // B*N tokens
#define HH 1024    // hidden
#define DD 2048    // expert inner dim
#define EE 8       // experts

typedef float f32x4 __attribute__((ext_vector_type(4)));
typedef __bf16 bf16x8 __attribute__((ext_vector_type(8)));

__device__ __forceinline__ unsigned short f2bf(float f) {
  union { float f; unsigned u; } v; v.f = f;
  unsigned r = v.u + 0x7FFFu + ((v.u >> 16) & 1u);  // RNE
  return (unsigned short)(r >> 16);
}

// ---------------- init: zero accumulators ----------------
__global__ void k_init(int* counts, float* probs_sum, float* ent_sum) {
  int t = threadIdx.x;
  if (t < EE) { counts[t] = 0; probs_sum[t] = 0.f; }
  if (t == 0) *ent_sum = 0.f;
}

// ---------------- x fp32 -> bf16 ----------------
__global__ __launch_bounds__(256) void k_convert_x(const float* __restrict__ x,
                                                   unsigned short* __restrict__ xb) {
  size_t i = (size_t)(blockIdx.x * 256 + threadIdx.x) * 4;
  float4 v = *(const float4*)(x + i);
  ushort4 o;
  o.x = f2bf(v.x); o.y = f2bf(v.y); o.z = f2bf(v.z); o.w = f2bf(v.w);
  *(ushort4*)(xb + i) = o;
}

// ---------------- transpose+convert weights: [E][R][C] fp32 -> [E][C][R] bf16 ----------------
__global__ __launch_bounds__(256) void k_transpose(const float* __restrict__ src,
                                                   unsigned short* __restrict__ dst,
                                                   int R, int C) {
  __shared__ float tile[32][33];
  int tilesC = C / 32, tilesR = R / 32;
  int bid = blockIdx.x;
  int e = bid / (tilesR * tilesC);
  int rem = bid % (tilesR * tilesC);
  int tr = rem / tilesC, tc = rem % tilesC;
  const float* s = src + (size_t)e * R * C;
  unsigned short* d = dst + (size_t)e * R * C;
  int tx = threadIdx.x & 31, ty = threadIdx.x >> 5;
#pragma unroll
  for (int i = 0; i < 4; ++i)
    tile[ty + i * 8][tx] = s[(size_t)(tr * 32 + ty + i * 8) * C + tc * 32 + tx];
  __syncthreads();
#pragma unroll
  for (int i = 0; i < 4; ++i) {
    int rr = ty + i * 8;
    d[(size_t)(tc * 32 + rr) * R + tr * 32 + tx] = f2bf(tile[tx][rr]);
  }
}

// ---------------- router: fp64 logits, softmax, argmax, loss partials ----------------
__global__ __launch_bounds__(256) void k_router(const float* __restrict__ x,
                                                const float* __restrict__ Wr,
                                                const float* __restrict__ br,
                                                int* __restrict__ eidx,
                                                float* __restrict__ probs_sum,
                                                float* __restrict__ ent_sum,
                                                int* __restrict__ counts) {
  __shared__ float s_p[EE];
  __shared__ int   s_c[EE];
  __shared__ float s_e;
  int tid = threadIdx.x;
  if (tid < EE) { s_p[tid] = 0.f; s_c[tid] = 0; }
  if (tid == 0) s_e = 0.f;
  __syncthreads();
  int lane = tid & 63, w = tid >> 6;
  for (int tt = 0; tt < 4; ++tt) {
    int token = blockIdx.x * 16 + w * 4 + tt;
    double acc[EE];
#pragma unroll
    for (int e = 0; e < EE; ++e) acc[e] = 0.0;
    const float* xr = x + (size_t)token * HH;
    for (int i = 0; i < 16; ++i) {
      int hh = i * 64 + lane;
      double xv = (double)xr[hh];
      const float* wr = Wr + (size_t)hh * EE;
#pragma unroll
      for (int e = 0; e < EE; ++e) acc[e] += xv * (double)wr[e];
    }
#pragma unroll
    for (int off = 32; off > 0; off >>= 1) {
#pragma unroll
      for (int e = 0; e < EE; ++e) acc[e] += __shfl_down(acc[e], off);
    }
    if (lane == 0) {
      double l[EE];
#pragma unroll
      for (int e = 0; e < EE; ++e) l[e] = acc[e] + (double)br[e];
      double m = l[0]; int am = 0;
#pragma unroll
      for (int e = 1; e < EE; ++e) { if (l[e] > m) { m = l[e]; am = e; } }  // first-max semantics
      double p[EE]; double s = 0.0;
#pragma unroll
      for (int e = 0; e < EE; ++e) { p[e] = exp(l[e] - m); s += p[e]; }
      double inv = 1.0 / s; double ent = 0.0;
#pragma unroll
      for (int e = 0; e < EE; ++e) { p[e] *= inv; ent -= p[e] * log(p[e] + 1e-8); }
      eidx[token] = am;
#pragma unroll
      for (int e = 0; e < EE; ++e) atomicAdd(&s_p[e], (float)p[e]);
      atomicAdd(&s_e, (float)ent);
      atomicAdd(&s_c[am], 1);
    }
  }
  __syncthreads();
  if (tid < EE) { atomicAdd(&probs_sum[tid], s_p[tid]); atomicAdd(&counts[tid], s_c[tid]); }
  if (tid == 0) atomicAdd(ent_sum, s_e);
}

// ---------------- scan: offsets, cursors, tile descriptors, loss outputs ----------------
__global__ void k_scan(const int* counts, const float* probs_sum, const float* ent_sum,
                       int* offsets, int* cursor,
                       int* tileE, int* tileR0, int* tileEnd, int* nTiles,
                       float* out_scalars) {
  if (threadIdx.x != 0) return;
  int off = 0, nt = 0;
  for (int e = 0; e < EE; ++e) {
    offsets[e] = off; cursor[e] = off;
    int c = counts[e];
    for (int r = 0; r < c; r += 64) {
      tileE[nt] = e; tileR0[nt] = off + r; tileEnd[nt] = off + c; ++nt;
    }
    off += c;
  }
  offsets[EE] = off;
  *nTiles = nt;
  float bal = 0.f;
  for (int e = 0; e < EE; ++e) { float pi = probs_sum[e] / (float)TT; bal += pi * pi; }
  out_scalars[0] = (float)EE * bal;      // balance_loss
  out_scalars[1] = *ent_sum / (float)TT; // entropy_loss
  for (int e = 0; e < EE; ++e) out_scalars[2 + e] = (float)counts[e];  // tokens_per_expert
}

// ---------------- build permutation (expert-grouped token order) ----------------
__global__ __launch_bounds__(256) void k_perm(const int* __restrict__ eidx,
                                              int* cursor, int* __restrict__ perm) {
  int t = blockIdx.x * 256 + threadIdx.x;
  int lane = threadIdx.x & 63;
  int mye = eidx[t];
  int pos = 0;
#pragma unroll
  for (int e = 0; e < EE; ++e) {
    unsigned long long mask = __ballot(mye == e);
    if (mask == 0ull) continue;
    int leader = __ffsll(mask) - 1;
    int base = 0;
    if (lane == leader) base = atomicAdd(&cursor[e], __popcll(mask));
    base = __shfl(base, leader);
    if (mye == e) pos = base + (int)__popcll(mask & ((1ull << lane) - 1ull));
  }
  perm[pos] = t;
}

// ---------------- GEMM1: h = gelu(gather(x) @ W1[e] + b1[e]), bf16 out ----------------
__global__ __launch_bounds__(256) void k_gemm1(const unsigned short* __restrict__ xb,
                                               const unsigned short* __restrict__ Wt1,
                                               const float* __restrict__ b1,
                                               const int* __restrict__ perm,
                                               const int* __restrict__ tileE,
                                               const int* __restrict__ tileR0,
                                               const int* __restrict__ tileEnd,
                                               const int* __restrict__ nTiles,
                                               unsigned short* __restrict__ hbuf) {
  int tile = blockIdx.y;
  if (tile >= *nTiles) return;
  int e = tileE[tile], r0 = tileR0[tile], rend = tileEnd[tile];
  int c0 = blockIdx.x * 64;
  __shared__ __align__(16) unsigned short As[64][32];
  __shared__ __align__(16) unsigned short Bs[64][32];
  int tid = threadIdx.x, lane = tid & 63, w = tid >> 6;
  int wr = w >> 1, wc = w & 1;
  int arow = tid >> 2, aseg = tid & 3;
  int gRow = r0 + arow;
  int tok = perm[(gRow < rend) ? gRow : r0];
  const uint4* aSrc = (const uint4*)(xb + (size_t)tok * HH) + aseg;
  const uint4* bSrc = (const uint4*)(Wt1 + (size_t)e * (DD * HH) + (size_t)(c0 + arow) * HH) + aseg;
  f32x4 acc00 = {0,0,0,0}, acc01 = {0,0,0,0}, acc10 = {0,0,0,0}, acc11 = {0,0,0,0};
  int quad = lane >> 4, l16 = lane & 15;
  for (int k0 = 0; k0 < HH; k0 += 32) {
    uint4 av = aSrc[k0 >> 3];
    uint4 bv = bSrc[k0 >> 3];
    __syncthreads();
    *(uint4*)&As[arow][aseg * 8] = av;
    *(uint4*)&Bs[arow][aseg * 8] = bv;
    __syncthreads();
    bf16x8 a0 = *(const bf16x8*)&As[wr * 32 + l16][quad * 8];
    bf16x8 a1 = *(const bf16x8*)&As[wr * 32 + 16 + l16][quad * 8];
    bf16x8 b0 = *(const bf16x8*)&Bs[wc * 32 + l16][quad * 8];
    bf16x8 b1v = *(const bf16x8*)&Bs[wc * 32 + 16 + l16][quad * 8];
    acc00 = __builtin_amdgcn_mfma_f32_16x16x32_bf16(a0, b0,  acc00, 0, 0, 0);
    acc01 = __builtin_amdgcn_mfma_f32_16x16x32_bf16(a0, b1v, acc01, 0, 0, 0);
    acc10 = __builtin_amdgcn_mfma_f32_16x16x32_bf16(a1, b0,  acc10, 0, 0, 0);
    acc11 = __builtin_amdgcn_mfma_f32_16x16x32_bf16(a1, b1v, acc11, 0, 0, 0);
  }
  f32x4 accs[2][2] = {{acc00, acc01}, {acc10, acc11}};
#pragma unroll
  for (int i = 0; i < 2; ++i) {
#pragma unroll
    for (int j = 0; j < 2; ++j) {
#pragma unroll
      for (int r = 0; r < 4; ++r) {
        int row = wr * 32 + i * 16 + quad * 4 + r;
        int gr = r0 + row;
        if (gr < rend) {
          int col = c0 + wc * 32 + j * 16 + l16;
          float v = accs[i][j][r] + b1[e * DD + col];
          v = 0.5f * v * (1.0f + erff(v * 0.70710678118654752f));  // exact erf GELU
          hbuf[(size_t)gr * DD + col] = f2bf(v);
        }
      }
    }
  }
}

// ---------------- GEMM2: out[tok] = x[tok] + h @ W2[e] + b2[e], scattered fp32 ----------------
__global__ __launch_bounds__(256) void k_gemm2(const unsigned short* __restrict__ hbuf,
                                               const unsigned short* __restrict__ Wt2,
                                               const float* __restrict__ b2,
                                               const float* __restrict__ x,
                                               const int* __restrict__ perm,
                                               const int* __restrict__ tileE,
                                               const int* __restrict__ tileR0,
                                               const int* __restrict__ tileEnd,
                                               const int* __restrict__ nTiles,
                                               float* __restrict__ outp) {
  int tile = blockIdx.y;
  if (tile >= *nTiles) return;
  int e = tileE[tile], r0 = tileR0[tile], rend = tileEnd[tile];
  int c0 = blockIdx.x * 64;
  __shared__ __align__(16) unsigned short As[64][32];
  __shared__ __align__(16) unsigned short Bs[64][32];
  int tid = threadIdx.x, lane = tid & 63, w = tid >> 6;
  int wr = w >> 1, wc = w & 1;
  int arow = tid >> 2, aseg = tid & 3;
  int gRow = r0 + arow;
  const uint4* aSrc = (const uint4*)(hbuf + (size_t)((gRow < rend) ? gRow : r0) * DD) + aseg;
  const uint4* bSrc = (const uint4*)(Wt2 + (size_t)e * (HH * DD) + (size_t)(c0 + arow) * DD) + aseg;
  f32x4 acc00 = {0,0,0,0}, acc01 = {0,0,0,0}, acc10 = {0,0,0,0}, acc11 = {0,0,0,0};
  int quad = lane >> 4, l16 = lane & 15;
  for (int k0 = 0; k0 < DD; k0 += 32) {
    uint4 av = aSrc[k0 >> 3];
    uint4 bv = bSrc[k0 >> 3];
    __syncthreads();
    *(uint4*)&As[arow][aseg * 8] = av;
    *(uint4*)&Bs[arow][aseg * 8] = bv;
    __syncthreads();
    bf16x8 a0 = *(const bf16x8*)&As[wr * 32 + l16][quad * 8];
    bf16x8 a1 = *(const bf16x8*)&As[wr * 32 + 16 + l16][quad * 8];
    bf16x8 b0 = *(const bf16x8*)&Bs[wc * 32 + l16][quad * 8];
    bf16x8 b1v = *(const bf16x8*)&Bs[wc * 32 + 16 + l16][quad * 8];
    acc00 = __builtin_amdgcn_mfma_f32_16x16x32_bf16(a0, b0,  acc00, 0, 0, 0);
    acc01 = __builtin_amdgcn_mfma_f32_16x16x32_bf16(a0, b1v, acc01, 0, 0, 0);
    acc10 = __builtin_amdgcn_mfma_f32_16x16x32_bf16(a1, b0,  acc10, 0, 0, 0);
    acc11 = __builtin_amdgcn_mfma_f32_16x16x32_bf16(a1, b1v, acc11, 0, 0, 0);
  }
  f32x4 accs[2][2] = {{acc00, acc01}, {acc10, acc11}};
#pragma unroll
  for (int i = 0; i < 2; ++i) {
#pragma unroll
    for (int j = 0; j < 2; ++j) {
#pragma unroll
      for (int r = 0; r < 4; ++r) {
        int row = wr * 32 + i * 16 + quad * 4 + r;
        int gr = r0 + row;
        if (gr < rend) {
          int tok = perm[gr];
          int col = c0 + wc * 32 + j * 16 + l16;
          size_t oi = (size_t)tok * HH + col;
          outp[oi] = x[oi] + b2[e * HH + col] + accs[i][j][r];
        }
      }
    }
  }
}

extern "C" void kernel_launch(void* const* d_in, const int* in_sizes, int n_in,
                              void* d_out, int out_size, void* d_ws, size_t ws_size,
                              hipStream_t stream) {
  const float* x  = (const float*)d_in[0];
  const float* Wr = (const float*)d_in[1];
  const float* br = (const float*)d_in[2];
  const float* W1 = (const float*)d_in[3];
  const float* b1 = (const float*)d_in[4];
  const float* W2 = (const float*)d_in[5];
  const float* b2 = (const float*)d_in[6];
  float* outp = (float*)d_out;

  char* ws = (char*)d_ws;
  int*   counts    = (int*)(ws + 0);
  int*   cursor    = (int*)(ws + 64);
  int*   nTiles    = (int*)(ws + 128);
  float* probs_sum = (float*)(ws + 192);
  float* ent_sum   = (float*)(ws + 256);
  int*   offsets   = (int*)(ws + 320);
  int*   tileE     = (int*)(ws + 512);    // up to 264 tiles
  int*   tileR0    = (int*)(ws + 2048);
  int*   tileEnd   = (int*)(ws + 3584);
  int*   eidx      = (int*)(ws + 8192);
  int*   perm      = (int*)(ws + 8192 + 4 * (size_t)TT);
  size_t off = 8192 + 8 * (size_t)TT;
  unsigned short* xb   = (unsigned short*)(ws + off); off += (size_t)TT * HH * 2;        // 32 MB
  unsigned short* Wt1  = (unsigned short*)(ws + off); off += (size_t)EE * DD * HH * 2;   // 32 MB
  unsigned short* Wt2  = (unsigned short*)(ws + off); off += (size_t)EE * HH * DD * 2;   // 32 MB
  unsigned short* hbuf = (unsigned short*)(ws + off); off += (size_t)TT * DD * 2;        // 64 MB

  k_init<<<1, 64, 0, stream>>>(counts, probs_sum, ent_sum);
  k_convert_x<<<(TT * HH / 4) / 256, 256, 0, stream>>>(x, xb);
  k_transpose<<<EE * (HH / 32) * (DD / 32), 256, 0, stream>>>(W1, Wt1, HH, DD);
  k_transpose<<<EE * (DD / 32) * (HH / 32), 256, 0, stream>>>(W2, Wt2, DD, HH);
  k_router<<<TT / 16, 256, 0, stream>>>(x, Wr, br, eidx, probs_sum, ent_sum, counts);
  k_scan<<<1, 64, 0, stream>>>(counts, probs_sum, ent_sum, offsets, cursor,
                               tileE, tileR0, tileEnd, nTiles, outp + (size_t)TT * HH);
  k_perm<<<TT / 256, 256, 0, stream>>>(eidx, cursor, perm);
  dim3 g1(DD / 64, 264);
  k_gemm1<<<g1, 256, 0, stream>>>(xb, Wt1, b1, perm, tileE, tileR0, tileEnd, nTiles, hbuf);
  dim3 g2(HH / 64, 264);
  k_gemm2<<<g2, 256, 0, stream>>>(hbuf, Wt2, b2, x, perm, tileE, tileR0, tileEnd, nTiles, outp);
}

// Round 2
// 598.288 us; speedup vs baseline: 1.1992x; 1.1992x over previous
//
#include <hip/hip_runtime.h>
#include <math.h>

// Problem constants
#define TT 16384   // B*N tokens
#define HH 1024    // hidden
#define DD 2048    // expert inner dim
#define EE 8       // experts
#define MAXTILES 160  // >= EE + TT/128

typedef float f32x4 __attribute__((ext_vector_type(4)));
typedef __bf16 bf16x8 __attribute__((ext_vector_type(8)));

__device__ __forceinline__ unsigned short f2bf(float f) {
  union { float f; unsigned u; } v; v.f = f;
  unsigned r = v.u + 0x7FFFu + ((v.u >> 16) & 1u);  // RNE
  return (unsigned short)(r >> 16);
}

// async global->LDS 16B per lane; LDS dest = wave-uniform base + lane*16
__device__ __forceinline__ void gl2lds16(const unsigned short* g, unsigned short* l) {
  __builtin_amdgcn_global_load_lds(
      (const __attribute__((address_space(1))) void*)g,
      (__attribute__((address_space(3))) void*)l, 16, 0, 0);
}

// ---------------- init: zero accumulators ----------------
__global__ void k_init(int* counts, float* probs_sum, float* ent_sum) {
  int t = threadIdx.x;
  if (t < EE) { counts[t] = 0; probs_sum[t] = 0.f; }
  if (t == 0) *ent_sum = 0.f;
}

// ---------------- transpose+convert weights: [E][R][C] fp32 -> [E][C][R] bf16 ----------------
__global__ __launch_bounds__(256) void k_transpose(const float* __restrict__ src,
                                                   unsigned short* __restrict__ dst,
                                                   int R, int C) {
  __shared__ float tile[32][33];
  int tilesC = C / 32, tilesR = R / 32;
  int bid = blockIdx.x;
  int e = bid / (tilesR * tilesC);
  int rem = bid % (tilesR * tilesC);
  int tr = rem / tilesC, tc = rem % tilesC;
  const float* s = src + (size_t)e * R * C;
  unsigned short* d = dst + (size_t)e * R * C;
  int tx = threadIdx.x & 31, ty = threadIdx.x >> 5;
#pragma unroll
  for (int i = 0; i < 4; ++i)
    tile[ty + i * 8][tx] = s[(size_t)(tr * 32 + ty + i * 8) * C + tc * 32 + tx];
  __syncthreads();
#pragma unroll
  for (int i = 0; i < 4; ++i) {
    int rr = ty + i * 8;
    d[(size_t)(tc * 32 + rr) * R + tr * 32 + tx] = f2bf(tile[tx][rr]);
  }
}

// ---------------- router: fp64 logits, softmax, argmax, loss partials, x->bf16 fused ----------------
__global__ __launch_bounds__(256) void k_router(const float* __restrict__ x,
                                                const float* __restrict__ Wr,
                                                const float* __restrict__ br,
                                                int* __restrict__ eidx,
                                                float* __restrict__ probs_sum,
                                                float* __restrict__ ent_sum,
                                                int* __restrict__ counts,
                                                unsigned short* __restrict__ xb) {
  __shared__ float s_p[EE];
  __shared__ int   s_c[EE];
  __shared__ float s_e;
  int tid = threadIdx.x;
  if (tid < EE) { s_p[tid] = 0.f; s_c[tid] = 0; }
  if (tid == 0) s_e = 0.f;
  __syncthreads();
  int lane = tid & 63, w = tid >> 6;
  for (int tt = 0; tt < 4; ++tt) {
    int token = blockIdx.x * 16 + w * 4 + tt;
    double acc[EE];
#pragma unroll
    for (int e = 0; e < EE; ++e) acc[e] = 0.0;
    const float* xr = x + (size_t)token * HH;
    unsigned short* xo = xb + (size_t)token * HH;
    for (int i = 0; i < 16; ++i) {
      int hh = i * 64 + lane;
      float xf = xr[hh];
      xo[hh] = f2bf(xf);               // fused fp32->bf16 conversion
      double xv = (double)xf;
      const float* wr = Wr + (size_t)hh * EE;
#pragma unroll
      for (int e = 0; e < EE; ++e) acc[e] += xv * (double)wr[e];
    }
#pragma unroll
    for (int off = 32; off > 0; off >>= 1) {
#pragma unroll
      for (int e = 0; e < EE; ++e) acc[e] += __shfl_down(acc[e], off);
    }
    if (lane == 0) {
      double l[EE];
#pragma unroll
      for (int e = 0; e < EE; ++e) l[e] = acc[e] + (double)br[e];
      double m = l[0]; int am = 0;
#pragma unroll
      for (int e = 1; e < EE; ++e) { if (l[e] > m) { m = l[e]; am = e; } }  // first-max semantics
      double p[EE]; double s = 0.0;
#pragma unroll
      for (int e = 0; e < EE; ++e) { p[e] = exp(l[e] - m); s += p[e]; }
      double inv = 1.0 / s; double ent = 0.0;
#pragma unroll
      for (int e = 0; e < EE; ++e) { p[e] *= inv; ent -= p[e] * log(p[e] + 1e-8); }
      eidx[token] = am;
#pragma unroll
      for (int e = 0; e < EE; ++e) atomicAdd(&s_p[e], (float)p[e]);
      atomicAdd(&s_e, (float)ent);
      atomicAdd(&s_c[am], 1);
    }
  }
  __syncthreads();
  if (tid < EE) { atomicAdd(&probs_sum[tid], s_p[tid]); atomicAdd(&counts[tid], s_c[tid]); }
  if (tid == 0) atomicAdd(ent_sum, s_e);
}

// ---------------- scan: offsets, cursors, 128-row tile descriptors, loss outputs ----------------
__global__ void k_scan(const int* counts, const float* probs_sum, const float* ent_sum,
                       int* offsets, int* cursor,
                       int* tileE, int* tileR0, int* tileEnd, int* nTiles,
                       float* out_scalars) {
  if (threadIdx.x != 0) return;
  int off = 0, nt = 0;
  for (int e = 0; e < EE; ++e) {
    offsets[e] = off; cursor[e] = off;
    int c = counts[e];
    for (int r = 0; r < c; r += 128) {
      tileE[nt] = e; tileR0[nt] = off + r; tileEnd[nt] = off + c; ++nt;
    }
    off += c;
  }
  offsets[EE] = off;
  *nTiles = nt;
  float bal = 0.f;
  for (int e = 0; e < EE; ++e) { float pi = probs_sum[e] / (float)TT; bal += pi * pi; }
  out_scalars[0] = (float)EE * bal;      // balance_loss
  out_scalars[1] = *ent_sum / (float)TT; // entropy_loss
  for (int e = 0; e < EE; ++e) out_scalars[2 + e] = (float)counts[e];  // tokens_per_expert
}

// ---------------- build permutation (expert-grouped token order) ----------------
__global__ __launch_bounds__(256) void k_perm(const int* __restrict__ eidx,
                                              int* cursor, int* __restrict__ perm) {
  int t = blockIdx.x * 256 + threadIdx.x;
  int lane = threadIdx.x & 63;
  int mye = eidx[t];
  int pos = 0;
#pragma unroll
  for (int e = 0; e < EE; ++e) {
    unsigned long long mask = __ballot(mye == e);
    if (mask == 0ull) continue;
    int leader = __ffsll(mask) - 1;
    int base = 0;
    if (lane == leader) base = atomicAdd(&cursor[e], __popcll(mask));
    base = __shfl(base, leader);
    if (mye == e) pos = base + (int)__popcll(mask & ((1ull << lane) - 1ull));
  }
  perm[pos] = t;
}

// ================= 128x128-tile MFMA GEMMs (m97 structure) =================
// Per K-step(32): stage A(128x32)+B(128x32) via global_load_lds x4/wave,
// barrier, 8x ds_read_b128 frags, 16 MFMA 16x16x32, barrier.

// GEMM1: h = gelu(gather_perm(x) @ W1[e]^T-layout + b1[e]) -> bf16 hbuf (permuted rows)
__global__ __launch_bounds__(256) void k_gemm1(const unsigned short* __restrict__ xb,
                                               const unsigned short* __restrict__ Wt1,
                                               const float* __restrict__ b1,
                                               const int* __restrict__ perm,
                                               const int* __restrict__ tileE,
                                               const int* __restrict__ tileR0,
                                               const int* __restrict__ tileEnd,
                                               const int* __restrict__ nTiles,
                                               unsigned short* __restrict__ hbuf) {
  int tile = blockIdx.y;
  if (tile >= *nTiles) return;
  int e = tileE[tile], r0 = tileR0[tile], rend = tileEnd[tile];
  int c0 = blockIdx.x * 128;
  __shared__ __align__(16) unsigned short As[128 * 32];
  __shared__ __align__(16) unsigned short Bs[128 * 32];
  int tid = threadIdx.x, lane = tid & 63, w = tid >> 6;
  int wr = w >> 1, wc = w & 1;
  int quad = lane >> 4, l16 = lane & 15;
  // staging: wave w covers tile rows [w*32, w*32+32) in two 16-row instructions
  int srow = lane >> 2, seg = lane & 3;
  int ar0 = w * 32 + srow, ar1 = ar0 + 16;
  int g0 = r0 + ar0; if (g0 >= rend) g0 = rend - 1;
  int g1 = r0 + ar1; if (g1 >= rend) g1 = rend - 1;
  const unsigned short* aG0 = xb + (size_t)perm[g0] * HH + seg * 8;
  const unsigned short* aG1 = xb + (size_t)perm[g1] * HH + seg * 8;
  const unsigned short* bBase = Wt1 + (size_t)e * ((size_t)DD * HH);
  const unsigned short* bG0 = bBase + (size_t)(c0 + ar0) * HH + seg * 8;
  const unsigned short* bG1 = bBase + (size_t)(c0 + ar1) * HH + seg * 8;
  unsigned short* aL0 = &As[(w * 32 + 0) * 32];
  unsigned short* aL1 = &As[(w * 32 + 16) * 32];
  unsigned short* bL0 = &Bs[(w * 32 + 0) * 32];
  unsigned short* bL1 = &Bs[(w * 32 + 16) * 32];
  f32x4 acc[4][4] = {};
  for (int k0 = 0; k0 < HH; k0 += 32) {
    gl2lds16(aG0 + k0, aL0);
    gl2lds16(aG1 + k0, aL1);
    gl2lds16(bG0 + k0, bL0);
    gl2lds16(bG1 + k0, bL1);
    __syncthreads();   // compiler drains vmcnt(0) before s_barrier
    bf16x8 a[4], b[4];
#pragma unroll
    for (int i = 0; i < 4; ++i)
      a[i] = *(const bf16x8*)&As[(wr * 64 + i * 16 + l16) * 32 + quad * 8];
#pragma unroll
    for (int j = 0; j < 4; ++j)
      b[j] = *(const bf16x8*)&Bs[(wc * 64 + j * 16 + l16) * 32 + quad * 8];
#pragma unroll
    for (int i = 0; i < 4; ++i)
#pragma unroll
      for (int j = 0; j < 4; ++j)
        acc[i][j] = __builtin_amdgcn_mfma_f32_16x16x32_bf16(a[i], b[j], acc[i][j], 0, 0, 0);
    __syncthreads();
  }
  float bias[4];
#pragma unroll
  for (int j = 0; j < 4; ++j) bias[j] = b1[e * DD + c0 + wc * 64 + j * 16 + l16];
#pragma unroll
  for (int i = 0; i < 4; ++i) {
#pragma unroll
    for (int r = 0; r < 4; ++r) {
      int gr = r0 + wr * 64 + i * 16 + quad * 4 + r;
      if (gr < rend) {
#pragma unroll
        for (int j = 0; j < 4; ++j) {
          int col = c0 + wc * 64 + j * 16 + l16;
          float v = acc[i][j][r] + bias[j];
          v = 0.5f * v * (1.0f + erff(v * 0.70710678118654752f));  // exact erf GELU
          hbuf[(size_t)gr * DD + col] = f2bf(v);
        }
      }
    }
  }
}

// GEMM2: out[perm[row]] = x + h @ W2[e]^T-layout + b2[e]  (A rows contiguous in hbuf)
__global__ __launch_bounds__(256) void k_gemm2(const unsigned short* __restrict__ hbuf,
                                               const unsigned short* __restrict__ Wt2,
                                               const float* __restrict__ b2,
                                               const float* __restrict__ x,
                                               const int* __restrict__ perm,
                                               const int* __restrict__ tileE,
                                               const int* __restrict__ tileR0,
                                               const int* __restrict__ tileEnd,
                                               const int* __restrict__ nTiles,
                                               float* __restrict__ outp) {
  int tile = blockIdx.y;
  if (tile >= *nTiles) return;
  int e = tileE[tile], r0 = tileR0[tile], rend = tileEnd[tile];
  int c0 = blockIdx.x * 128;
  __shared__ __align__(16) unsigned short As[128 * 32];
  __shared__ __align__(16) unsigned short Bs[128 * 32];
  int tid = threadIdx.x, lane = tid & 63, w = tid >> 6;
  int wr = w >> 1, wc = w & 1;
  int quad = lane >> 4, l16 = lane & 15;
  int srow = lane >> 2, seg = lane & 3;
  int ar0 = w * 32 + srow, ar1 = ar0 + 16;
  int g0 = r0 + ar0; if (g0 >= rend) g0 = rend - 1;
  int g1 = r0 + ar1; if (g1 >= rend) g1 = rend - 1;
  const unsigned short* aG0 = hbuf + (size_t)g0 * DD + seg * 8;
  const unsigned short* aG1 = hbuf + (size_t)g1 * DD + seg * 8;
  const unsigned short* bBase = Wt2 + (size_t)e * ((size_t)HH * DD);
  const unsigned short* bG0 = bBase + (size_t)(c0 + ar0) * DD + seg * 8;
  const unsigned short* bG1 = bBase + (size_t)(c0 + ar1) * DD + seg * 8;
  unsigned short* aL0 = &As[(w * 32 + 0) * 32];
  unsigned short* aL1 = &As[(w * 32 + 16) * 32];
  unsigned short* bL0 = &Bs[(w * 32 + 0) * 32];
  unsigned short* bL1 = &Bs[(w * 32 + 16) * 32];
  f32x4 acc[4][4] = {};
  for (int k0 = 0; k0 < DD; k0 += 32) {
    gl2lds16(aG0 + k0, aL0);
    gl2lds16(aG1 + k0, aL1);
    gl2lds16(bG0 + k0, bL0);
    gl2lds16(bG1 + k0, bL1);
    __syncthreads();
    bf16x8 a[4], b[4];
#pragma unroll
    for (int i = 0; i < 4; ++i)
      a[i] = *(const bf16x8*)&As[(wr * 64 + i * 16 + l16) * 32 + quad * 8];
#pragma unroll
    for (int j = 0; j < 4; ++j)
      b[j] = *(const bf16x8*)&Bs[(wc * 64 + j * 16 + l16) * 32 + quad * 8];
#pragma unroll
    for (int i = 0; i < 4; ++i)
#pragma unroll
      for (int j = 0; j < 4; ++j)
        acc[i][j] = __builtin_amdgcn_mfma_f32_16x16x32_bf16(a[i], b[j], acc[i][j], 0, 0, 0);
    __syncthreads();
  }
  float bias[4];
#pragma unroll
  for (int j = 0; j < 4; ++j) bias[j] = b2[e * HH + c0 + wc * 64 + j * 16 + l16];
#pragma unroll
  for (int i = 0; i < 4; ++i) {
#pragma unroll
    for (int r = 0; r < 4; ++r) {
      int gr = r0 + wr * 64 + i * 16 + quad * 4 + r;
      if (gr < rend) {
        int tok = perm[gr];
#pragma unroll
        for (int j = 0; j < 4; ++j) {
          int col = c0 + wc * 64 + j * 16 + l16;
          size_t oi = (size_t)tok * HH + col;
          outp[oi] = x[oi] + bias[j] + acc[i][j][r];
        }
      }
    }
  }
}

extern "C" void kernel_launch(void* const* d_in, const int* in_sizes, int n_in,
                              void* d_out, int out_size, void* d_ws, size_t ws_size,
                              hipStream_t stream) {
  const float* x  = (const float*)d_in[0];
  const float* Wr = (const float*)d_in[1];
  const float* br = (const float*)d_in[2];
  const float* W1 = (const float*)d_in[3];
  const float* b1 = (const float*)d_in[4];
  const float* W2 = (const float*)d_in[5];
  const float* b2 = (const float*)d_in[6];
  float* outp = (float*)d_out;

  char* ws = (char*)d_ws;
  int*   counts    = (int*)(ws + 0);
  int*   cursor    = (int*)(ws + 64);
  int*   nTiles    = (int*)(ws + 128);
  float* probs_sum = (float*)(ws + 192);
  float* ent_sum   = (float*)(ws + 256);
  int*   offsets   = (int*)(ws + 320);
  int*   tileE     = (int*)(ws + 512);
  int*   tileR0    = (int*)(ws + 2048);
  int*   tileEnd   = (int*)(ws + 3584);
  int*   eidx      = (int*)(ws + 8192);
  int*   perm      = (int*)(ws + 8192 + 4 * (size_t)TT);
  size_t off = 8192 + 8 * (size_t)TT;
  unsigned short* xb   = (unsigned short*)(ws + off); off += (size_t)TT * HH * 2;        // 32 MB
  unsigned short* Wt1  = (unsigned short*)(ws + off); off += (size_t)EE * DD * HH * 2;   // 32 MB
  unsigned short* Wt2  = (unsigned short*)(ws + off); off += (size_t)EE * HH * DD * 2;   // 32 MB
  unsigned short* hbuf = (unsigned short*)(ws + off); off += (size_t)TT * DD * 2;        // 64 MB

  k_init<<<1, 64, 0, stream>>>(counts, probs_sum, ent_sum);
  k_transpose<<<EE * (HH / 32) * (DD / 32), 256, 0, stream>>>(W1, Wt1, HH, DD);
  k_transpose<<<EE * (DD / 32) * (HH / 32), 256, 0, stream>>>(W2, Wt2, DD, HH);
  k_router<<<TT / 16, 256, 0, stream>>>(x, Wr, br, eidx, probs_sum, ent_sum, counts, xb);
  k_scan<<<1, 64, 0, stream>>>(counts, probs_sum, ent_sum, offsets, cursor,
                               tileE, tileR0, tileEnd, nTiles, outp + (size_t)TT * HH);
  k_perm<<<TT / 256, 256, 0, stream>>>(eidx, cursor, perm);
  dim3 g1(DD / 128, MAXTILES);
  k_gemm1<<<g1, 256, 0, stream>>>(xb, Wt1, b1, perm, tileE, tileR0, tileEnd, nTiles, hbuf);
  dim3 g2(HH / 128, MAXTILES);
  k_gemm2<<<g2, 256, 0, stream>>>(hbuf, Wt2, b2, x, perm, tileE, tileR0, tileEnd, nTiles, outp);
}